// Round 2
// 1249.968 us; speedup vs baseline: 1.1298x; 1.1298x over previous
//
#include <hip/hip_runtime.h>
#include <stdint.h>

// Problem constants
#define B_DIM 4
#define T_DIM 2048
#define D_IN  4096
#define D_OUT 16384
#define M_DIM (B_DIM * T_DIM)            // 8192 tokens
#define NW    ((size_t)D_OUT * (size_t)D_IN)  // 67108864 weights

typedef __attribute__((ext_vector_type(4))) int v4i;

// ---------------------------------------------------------------------------
// Kernel 1: per-token absmax int8 quantization of x. (unchanged, bit-exact)
// ---------------------------------------------------------------------------
__global__ __launch_bounds__(256) void act_quant_kernel(
    const float* __restrict__ x, int8_t* __restrict__ xq,
    float* __restrict__ scales) {
  const int row = blockIdx.x;
  const float4* xr = (const float4*)(x + (size_t)row * D_IN);
  float4 v[4];
  float amax = 0.f;
#pragma unroll
  for (int c = 0; c < 4; ++c) {
    v[c] = xr[c * 256 + threadIdx.x];
    amax = fmaxf(amax, fmaxf(fmaxf(fabsf(v[c].x), fabsf(v[c].y)),
                             fmaxf(fabsf(v[c].z), fabsf(v[c].w))));
  }
#pragma unroll
  for (int off = 32; off > 0; off >>= 1)
    amax = fmaxf(amax, __shfl_down(amax, off, 64));
  __shared__ float smax[4];
  const int lane = threadIdx.x & 63, wave = threadIdx.x >> 6;
  if (lane == 0) smax[wave] = amax;
  __syncthreads();
  amax = fmaxf(fmaxf(smax[0], smax[1]), fmaxf(smax[2], smax[3]));
  const float scale = amax * (1.0f / 127.0f);
  const float denom = scale + 1e-8f;
  if (threadIdx.x == 0) scales[row] = scale;
  int* outp = (int*)(xq + (size_t)row * D_IN);
#pragma unroll
  for (int c = 0; c < 4; ++c) {
    int q0 = min(127, max(-128, __float2int_rn(v[c].x / denom)));
    int q1 = min(127, max(-128, __float2int_rn(v[c].y / denom)));
    int q2 = min(127, max(-128, __float2int_rn(v[c].z / denom)));
    int q3 = min(127, max(-128, __float2int_rn(v[c].w / denom)));
    outp[c * 256 + threadIdx.x] =
        (q0 & 255) | ((q1 & 255) << 8) | ((q2 & 255) << 16) | ((q3 & 255) << 24);
  }
}

// ---------------------------------------------------------------------------
// Kernel 2a: sum(|W|) in double. (unchanged)
// ---------------------------------------------------------------------------
__global__ __launch_bounds__(256) void wabs_kernel(const float* __restrict__ w,
                                                   double* __restrict__ out) {
  const float4* w4 = (const float4*)w;
  const size_t n4 = NW / 4;
  double acc = 0.0;
  for (size_t i = (size_t)blockIdx.x * blockDim.x + threadIdx.x; i < n4;
       i += (size_t)gridDim.x * blockDim.x) {
    float4 v = w4[i];
    acc += (double)fabsf(v.x) + (double)fabsf(v.y);
    acc += (double)fabsf(v.z) + (double)fabsf(v.w);
  }
#pragma unroll
  for (int off = 32; off > 0; off >>= 1) acc += __shfl_down(acc, off, 64);
  __shared__ double ssum[4];
  const int lane = threadIdx.x & 63, wave = threadIdx.x >> 6;
  if (lane == 0) ssum[wave] = acc;
  __syncthreads();
  if (threadIdx.x == 0) atomicAdd(out, ssum[0] + ssum[1] + ssum[2] + ssum[3]);
}

// ---------------------------------------------------------------------------
// Kernel 2b: ternarize weights. (unchanged, bit-exact)
// ---------------------------------------------------------------------------
__global__ __launch_bounds__(256) void wquant_kernel(
    const float* __restrict__ w, const double* __restrict__ sumAbs,
    int8_t* __restrict__ wq) {
  const float ws = (float)(*sumAbs / (double)NW) + 1e-8f;
  const float4* w4 = (const float4*)w;
  int* outp = (int*)wq;
  const size_t stride = (size_t)gridDim.x * blockDim.x;
  size_t i = (size_t)blockIdx.x * blockDim.x + threadIdx.x;
#pragma unroll
  for (int c = 0; c < 4; ++c, i += stride) {
    float4 v = w4[i];
    float t0 = v.x / ws, t1 = v.y / ws, t2 = v.z / ws, t3 = v.w / ws;
    int q0 = (fabsf(t0) > 0.5f) ? ((t0 > 0.f) ? 1 : -1) : 0;
    int q1 = (fabsf(t1) > 0.5f) ? ((t1 > 0.f) ? 1 : -1) : 0;
    int q2 = (fabsf(t2) > 0.5f) ? ((t2 > 0.f) ? 1 : -1) : 0;
    int q3 = (fabsf(t3) > 0.5f) ? ((t3 > 0.f) ? 1 : -1) : 0;
    outp[i] = (q0 & 255) | ((q1 & 255) << 8) | ((q2 & 255) << 16) | ((q3 & 255) << 24);
  }
}

// ---------------------------------------------------------------------------
// Kernel 3: int8 GEMM — 256x256 tile, 8-phase counted-vmcnt schedule
// (i8 port of the verified 8-phase bf16 template; byte-geometry identical:
//  BK = 128 bytes/row, half-tile = 64 rows = 8KB = 2 global_load_lds).
//
// 8 waves (512 thr) as 2M x 4N; per-wave 128x64 output; 2 K-tiles per
// main-loop iteration (phases 1-4: buf0, 5-8: buf1). Per phase:
//   {ds_read subtile || 2x global_load_lds prefetch} -> barrier ->
//   lgkmcnt(0) -> setprio(1) 16x mfma_i32_16x16x64_i8 setprio(0)
//   -> [vmcnt(6) @P4/P8] -> barrier.
// vmcnt(6): at P4 the 6 youngest outstanding loads are P2/P3/P4's =>
// prev-P6/P7/P8 + this-P1 (everything buf1 needs for P5-P7) are drained.
// At P8 the 6 youngest are P6/P7/P8's => P2..P5 (everything buf0 needs next
// iteration) are drained. Never vmcnt(0) in the loop.
//
// LDS XOR swizzle (both-sides, rule #21): 16B chunk c of row r stored at
// chunk c ^ (r&7); applied by inverse-swizzling the global SOURCE address
// (LDS dest stays linear for global_load_lds) and swizzling the ds_read
// address. ds_read_b128: per 16-lane quad, 8 distinct 16B slots x 2 lanes
// = all 32 banks busy, 2-way aliasing (free).
// ---------------------------------------------------------------------------
#define BM 256
#define BN 256
#define BKB 128                  // K-bytes per LDS tile (128 i8 = 2 MFMA K-steps)
#define NKT (D_IN / BKB)         // 32 K-tiles
// LDS layout (128 KiB total)
#define A0s 0
#define B0s 32768
#define A1s 65536
#define B1s 98304

#define BARRIER() __builtin_amdgcn_s_barrier()
#define VMWAIT(n) asm volatile("s_waitcnt vmcnt(" #n ")" ::: "memory")
#define LGKM0()   asm volatile("s_waitcnt lgkmcnt(0)" ::: "memory")

__global__ __launch_bounds__(512, 2) void gemm_i8_kernel(
    const int8_t* __restrict__ xq, const int8_t* __restrict__ wq,
    const float* __restrict__ scales, const float* __restrict__ bias,
    float* __restrict__ out) {
  __shared__ __align__(16) int8_t lds[131072];

  const int tid = threadIdx.x;
  const int lane = tid & 63;
  const int wave = tid >> 6;
  const int wr = wave >> 2;    // 0..1  (M)
  const int wc = wave & 3;     // 0..3  (N)
  const int quad = lane >> 4;  // 0..3  (K-chunk for frags; row-group for C)
  const int r16 = lane & 15;

  // XCD-aware bijective swizzle: 2048 wgs, 8 XCDs, 256 contiguous per XCD
  const int bid = blockIdx.x;
  const int swz = (bid & 7) * 256 + (bid >> 3);
  const int bm = (swz >> 6) * BM;  // 32 M-tiles
  const int bn = (swz & 63) * BN;  // 64 N-tiles

  // ---- staging: linear LDS dest, inverse-swizzled global source ----
  const int sr = tid >> 3;                                 // row in 64-row quarter
  const int scol = ((tid & 7) << 4) ^ ((sr & 7) << 4);     // pre-swizzled col
  const int8_t* gA = xq + (size_t)(bm + sr) * D_IN + scol;
  const int8_t* gB = wq + (size_t)(bn + sr) * D_IN + scol;

#define STAGE(opbase, gp, q, kt)                                          \
  __builtin_amdgcn_global_load_lds(                                       \
      (const __attribute__((address_space(1))) void*)((gp) +              \
          (size_t)(q) * (64 * D_IN) + (kt) * BKB),                        \
      (__attribute__((address_space(3))) void*)(lds + (opbase) +          \
          (q) * 8192 + tid * 16),                                         \
      16, 0, 0);

  // ---- fragment read addressing (swizzled) ----
  const int sw = (r16 & 7) << 4;
  int koff[2];
  koff[0] = (quad * 16) ^ sw;
  koff[1] = (quad * 16 + 64) ^ sw;
  const int arow = wr * 128 + r16;
  const int brow = wc * 64 + r16;

  v4i acc[8][4] = {};
  v4i a[4][2], b[4][2];

#define LDA(base, h)                                                      \
  _Pragma("unroll") for (int i = 0; i < 4; ++i) {                         \
    _Pragma("unroll") for (int kk = 0; kk < 2; ++kk)                      \
        a[i][kk] = *(const v4i*)&lds[(base) +                             \
            (arow + (h) * 64 + i * 16) * BKB + koff[kk]];                 \
  }
#define LDB(base, j0)                                                     \
  _Pragma("unroll") for (int j = 0; j < 2; ++j) {                         \
    _Pragma("unroll") for (int kk = 0; kk < 2; ++kk)                      \
        b[(j0) + j][kk] = *(const v4i*)&lds[(base) +                      \
            (brow + ((j0) + j) * 16) * BKB + koff[kk]];                   \
  }
#define MM(h, j0)                                                         \
  LGKM0();                                                                \
  __builtin_amdgcn_s_setprio(1);                                          \
  _Pragma("unroll") for (int kk = 0; kk < 2; ++kk) {                      \
    _Pragma("unroll") for (int i = 0; i < 4; ++i) {                       \
      _Pragma("unroll") for (int j = 0; j < 2; ++j)                       \
          acc[(h) * 4 + i][(j0) + j] =                                    \
              __builtin_amdgcn_mfma_i32_16x16x64_i8(                      \
                  a[i][kk], b[(j0) + j][kk],                              \
                  acc[(h) * 4 + i][(j0) + j], 0, 0, 0);                   \
    }                                                                     \
  }                                                                       \
  __builtin_amdgcn_s_setprio(0);

  // ---- prologue: tile0 -> buf0 (8 loads), tile1 minus A.q1q3 -> buf1 (6) ----
  STAGE(A0s, gA, 0, 0) STAGE(A0s, gA, 1, 0) STAGE(A0s, gA, 2, 0) STAGE(A0s, gA, 3, 0)
  STAGE(B0s, gB, 0, 0) STAGE(B0s, gB, 1, 0) STAGE(B0s, gB, 2, 0) STAGE(B0s, gB, 3, 0)
  STAGE(A1s, gA, 0, 1) STAGE(A1s, gA, 2, 1)
  STAGE(B1s, gB, 0, 1) STAGE(B1s, gB, 1, 1) STAGE(B1s, gB, 2, 1) STAGE(B1s, gB, 3, 1)
  VMWAIT(6);
  BARRIER();

#pragma unroll 1
  for (int t = 0; t < NKT / 2; ++t) {
    const int kt1 = 2 * t + 1;               // always in range
    const int kt2 = (2 * t + 2) & (NKT - 1); // wraps on last iter (harmless,
    const int kt3 = (2 * t + 3) & (NKT - 1); //  staged regions already consumed)
    // P1: Q(mh0,nh0) of buf0
    LDA(A0s, 0) LDB(B0s, 0)
    STAGE(A1s, gA, 1, kt1) STAGE(A1s, gA, 3, kt1)
    BARRIER();
    MM(0, 0)
    BARRIER();
    // P2: Q(mh0,nh1)
    LDB(B0s, 2)
    STAGE(A0s, gA, 0, kt2) STAGE(A0s, gA, 2, kt2)
    BARRIER();
    MM(0, 2)
    BARRIER();
    // P3: Q(mh1,nh1)
    LDA(A0s, 1)
    STAGE(B0s, gB, 0, kt2) STAGE(B0s, gB, 1, kt2)
    BARRIER();
    MM(1, 2)
    BARRIER();
    // P4: Q(mh1,nh0) — register-resident; gate buf1 readiness
    STAGE(B0s, gB, 2, kt2) STAGE(B0s, gB, 3, kt2)
    BARRIER();
    MM(1, 0)
    VMWAIT(6);
    BARRIER();
    // P5: Q(mh0,nh0) of buf1
    LDA(A1s, 0) LDB(B1s, 0)
    STAGE(A0s, gA, 1, kt2) STAGE(A0s, gA, 3, kt2)
    BARRIER();
    MM(0, 0)
    BARRIER();
    // P6: Q(mh0,nh1)
    LDB(B1s, 2)
    STAGE(A1s, gA, 0, kt3) STAGE(A1s, gA, 2, kt3)
    BARRIER();
    MM(0, 2)
    BARRIER();
    // P7: Q(mh1,nh1)
    LDA(A1s, 1)
    STAGE(B1s, gB, 0, kt3) STAGE(B1s, gB, 1, kt3)
    BARRIER();
    MM(1, 2)
    BARRIER();
    // P8: Q(mh1,nh0) — gate buf0 readiness for next iter
    STAGE(B1s, gB, 2, kt3) STAGE(B1s, gB, 3, kt3)
    BARRIER();
    MM(1, 0)
    VMWAIT(6);
    BARRIER();
  }
  // Drain stray prefetch DMAs before the block can exit / LDS be reused.
  VMWAIT(0);

  // Epilogue. C/D layout (shape-determined): col = lane&15, row = quad*4+reg
  float bs[4];
#pragma unroll
  for (int j = 0; j < 4; ++j) bs[j] = bias[bn + wc * 64 + j * 16 + r16];

#pragma unroll
  for (int i = 0; i < 8; ++i) {
#pragma unroll
    for (int reg = 0; reg < 4; ++reg) {
      const int m = bm + wr * 128 + i * 16 + quad * 4 + reg;
      const float s = scales[m];
      float* orow = out + (size_t)m * D_OUT + bn + wc * 64 + r16;
#pragma unroll
      for (int j = 0; j < 4; ++j) {
        orow[j * 16] = (float)acc[i][j][reg] * s + bs[j];
      }
    }
  }
}

// ---------------------------------------------------------------------------
extern "C" void kernel_launch(void* const* d_in, const int* in_sizes, int n_in,
                              void* d_out, int out_size, void* d_ws,
                              size_t ws_size, hipStream_t stream) {
  const float* x = (const float*)d_in[0];     // (4,2048,4096) fp32
  const float* w = (const float*)d_in[1];     // (16384,4096) fp32
  const float* bias = (const float*)d_in[2];  // (16384,) fp32
  float* out = (float*)d_out;                 // (4,2048,16384) fp32

  // workspace layout (~96 MB total)
  char* ws = (char*)d_ws;
  double* d_sum = (double*)ws;                          // 8 B @ 0
  float* d_scales = (float*)(ws + 256);                 // 32 KB @ 256
  int8_t* d_xq = (int8_t*)(ws + 33024);                 // 32 MB
  int8_t* d_wq = (int8_t*)(ws + 33024 + (size_t)M_DIM * D_IN);  // 64 MB

  hipMemsetAsync(d_sum, 0, sizeof(double), stream);

  act_quant_kernel<<<M_DIM, 256, 0, stream>>>(x, d_xq, d_scales);
  wabs_kernel<<<2048, 256, 0, stream>>>(w, d_sum);
  wquant_kernel<<<16384, 256, 0, stream>>>(w, d_sum, d_wq);
  gemm_i8_kernel<<<2048, 512, 0, stream>>>(d_xq, d_wq, d_scales, bias, out);
}

// Round 3
// 1248.584 us; speedup vs baseline: 1.1310x; 1.0011x over previous
//
#include <hip/hip_runtime.h>
#include <stdint.h>

// Problem constants
#define B_DIM 4
#define T_DIM 2048
#define D_IN  4096
#define D_OUT 16384
#define M_DIM (B_DIM * T_DIM)            // 8192 tokens
#define NW    ((size_t)D_OUT * (size_t)D_IN)  // 67108864 weights

typedef __attribute__((ext_vector_type(4))) int v4i;

// ---------------------------------------------------------------------------
// Kernel 1: per-token absmax int8 quantization of x. (unchanged, bit-exact)
// ---------------------------------------------------------------------------
__global__ __launch_bounds__(256) void act_quant_kernel(
    const float* __restrict__ x, int8_t* __restrict__ xq,
    float* __restrict__ scales) {
  const int row = blockIdx.x;
  const float4* xr = (const float4*)(x + (size_t)row * D_IN);
  float4 v[4];
  float amax = 0.f;
#pragma unroll
  for (int c = 0; c < 4; ++c) {
    v[c] = xr[c * 256 + threadIdx.x];
    amax = fmaxf(amax, fmaxf(fmaxf(fabsf(v[c].x), fabsf(v[c].y)),
                             fmaxf(fabsf(v[c].z), fabsf(v[c].w))));
  }
#pragma unroll
  for (int off = 32; off > 0; off >>= 1)
    amax = fmaxf(amax, __shfl_down(amax, off, 64));
  __shared__ float smax[4];
  const int lane = threadIdx.x & 63, wave = threadIdx.x >> 6;
  if (lane == 0) smax[wave] = amax;
  __syncthreads();
  amax = fmaxf(fmaxf(smax[0], smax[1]), fmaxf(smax[2], smax[3]));
  const float scale = amax * (1.0f / 127.0f);
  const float denom = scale + 1e-8f;
  if (threadIdx.x == 0) scales[row] = scale;
  int* outp = (int*)(xq + (size_t)row * D_IN);
#pragma unroll
  for (int c = 0; c < 4; ++c) {
    int q0 = min(127, max(-128, __float2int_rn(v[c].x / denom)));
    int q1 = min(127, max(-128, __float2int_rn(v[c].y / denom)));
    int q2 = min(127, max(-128, __float2int_rn(v[c].z / denom)));
    int q3 = min(127, max(-128, __float2int_rn(v[c].w / denom)));
    outp[c * 256 + threadIdx.x] =
        (q0 & 255) | ((q1 & 255) << 8) | ((q2 & 255) << 16) | ((q3 & 255) << 24);
  }
}

// ---------------------------------------------------------------------------
// Kernel 2a: per-block partial sum(|W|) in double. NO atomics — the single
// contended fp64 atomicAdd (device-scope, cross-XCD) was a serialization
// suspect for the ~705 us of non-GEMM time. Partials -> wsum_kernel.
// ---------------------------------------------------------------------------
__global__ __launch_bounds__(256) void wabs_kernel(const float* __restrict__ w,
                                                   double* __restrict__ partial) {
  const float4* w4 = (const float4*)w;
  const size_t n4 = NW / 4;
  double acc = 0.0;
  for (size_t i = (size_t)blockIdx.x * blockDim.x + threadIdx.x; i < n4;
       i += (size_t)gridDim.x * blockDim.x) {
    float4 v = w4[i];
    acc += (double)fabsf(v.x) + (double)fabsf(v.y);
    acc += (double)fabsf(v.z) + (double)fabsf(v.w);
  }
#pragma unroll
  for (int off = 32; off > 0; off >>= 1) acc += __shfl_down(acc, off, 64);
  __shared__ double ssum[4];
  const int lane = threadIdx.x & 63, wave = threadIdx.x >> 6;
  if (lane == 0) ssum[wave] = acc;
  __syncthreads();
  if (threadIdx.x == 0)
    partial[blockIdx.x] = ssum[0] + ssum[1] + ssum[2] + ssum[3];
}

// ---------------------------------------------------------------------------
// Kernel 2a': single-block deterministic reduction of the 2048 partials.
// ---------------------------------------------------------------------------
__global__ __launch_bounds__(256) void wsum_kernel(
    const double* __restrict__ partial, double* __restrict__ out) {
  double acc = 0.0;
  for (int i = threadIdx.x; i < 2048; i += 256) acc += partial[i];
#pragma unroll
  for (int off = 32; off > 0; off >>= 1) acc += __shfl_down(acc, off, 64);
  __shared__ double ssum[4];
  const int lane = threadIdx.x & 63, wave = threadIdx.x >> 6;
  if (lane == 0) ssum[wave] = acc;
  __syncthreads();
  if (threadIdx.x == 0) out[0] = ssum[0] + ssum[1] + ssum[2] + ssum[3];
}

// ---------------------------------------------------------------------------
// Kernel 2b: ternarize weights. (unchanged, bit-exact)
// ---------------------------------------------------------------------------
__global__ __launch_bounds__(256) void wquant_kernel(
    const float* __restrict__ w, const double* __restrict__ sumAbs,
    int8_t* __restrict__ wq) {
  const float ws = (float)(*sumAbs / (double)NW) + 1e-8f;
  const float4* w4 = (const float4*)w;
  int* outp = (int*)wq;
  const size_t stride = (size_t)gridDim.x * blockDim.x;
  size_t i = (size_t)blockIdx.x * blockDim.x + threadIdx.x;
#pragma unroll
  for (int c = 0; c < 4; ++c, i += stride) {
    float4 v = w4[i];
    float t0 = v.x / ws, t1 = v.y / ws, t2 = v.z / ws, t3 = v.w / ws;
    int q0 = (fabsf(t0) > 0.5f) ? ((t0 > 0.f) ? 1 : -1) : 0;
    int q1 = (fabsf(t1) > 0.5f) ? ((t1 > 0.f) ? 1 : -1) : 0;
    int q2 = (fabsf(t2) > 0.5f) ? ((t2 > 0.f) ? 1 : -1) : 0;
    int q3 = (fabsf(t3) > 0.5f) ? ((t3 > 0.f) ? 1 : -1) : 0;
    outp[i] = (q0 & 255) | ((q1 & 255) << 8) | ((q2 & 255) << 16) | ((q3 & 255) << 24);
  }
}

// ---------------------------------------------------------------------------
// Kernel 3: int8 GEMM — 256x256 tile, 8-phase counted-vmcnt schedule.
// Round-3 change: NO forced lgkmcnt(0) before the MFMA cluster — ds_reads
// are issued in consumption order (kk=0 frags first) and the compiler emits
// minimal counted lgkmcnt per consumer, so the tail of the LDS-read window
// overlaps the MFMA cluster instead of serializing with it. P2/P6's b23
// reads are hoisted into P1/P5 (registers free there; data gated by the
// preceding VMWAIT(6)+barrier). Stage schedule and vmcnt counting unchanged
// from the verified round-2 kernel.
// ---------------------------------------------------------------------------
#define BM 256
#define BN 256
#define BKB 128                  // K-bytes per LDS tile (128 i8 = 2 MFMA K-steps)
#define NKT (D_IN / BKB)         // 32 K-tiles
// LDS layout (128 KiB total)
#define A0s 0
#define B0s 32768
#define A1s 65536
#define B1s 98304

#define BARRIER() __builtin_amdgcn_s_barrier()
#define VMWAIT(n) asm volatile("s_waitcnt vmcnt(" #n ")" ::: "memory")

__global__ __launch_bounds__(512, 2) void gemm_i8_kernel(
    const int8_t* __restrict__ xq, const int8_t* __restrict__ wq,
    const float* __restrict__ scales, const float* __restrict__ bias,
    float* __restrict__ out) {
  __shared__ __align__(16) int8_t lds[131072];

  const int tid = threadIdx.x;
  const int lane = tid & 63;
  const int wave = tid >> 6;
  const int wr = wave >> 2;    // 0..1  (M)
  const int wc = wave & 3;     // 0..3  (N)
  const int quad = lane >> 4;  // 0..3  (K-chunk for frags; row-group for C)
  const int r16 = lane & 15;

  // XCD-aware bijective swizzle: 2048 wgs, 8 XCDs, 256 contiguous per XCD
  const int bid = blockIdx.x;
  const int swz = (bid & 7) * 256 + (bid >> 3);
  const int bm = (swz >> 6) * BM;  // 32 M-tiles
  const int bn = (swz & 63) * BN;  // 64 N-tiles

  // ---- staging: linear LDS dest, inverse-swizzled global source ----
  const int sr = tid >> 3;                                 // row in 64-row quarter
  const int scol = ((tid & 7) << 4) ^ ((sr & 7) << 4);     // pre-swizzled col
  const int8_t* gA = xq + (size_t)(bm + sr) * D_IN + scol;
  const int8_t* gB = wq + (size_t)(bn + sr) * D_IN + scol;

#define STAGE(opbase, gp, q, kt)                                          \
  __builtin_amdgcn_global_load_lds(                                       \
      (const __attribute__((address_space(1))) void*)((gp) +              \
          (size_t)(q) * (64 * D_IN) + (kt) * BKB),                        \
      (__attribute__((address_space(3))) void*)(lds + (opbase) +          \
          (q) * 8192 + tid * 16),                                         \
      16, 0, 0);

  // ---- fragment read addressing (swizzled) ----
  const int sw = (r16 & 7) << 4;
  int koff[2];
  koff[0] = (quad * 16) ^ sw;
  koff[1] = (quad * 16 + 64) ^ sw;
  const int arow = wr * 128 + r16;
  const int brow = wc * 64 + r16;

  v4i acc[8][4] = {};
  v4i a[4][2], b[4][2];

  // kk-granular read macros: issue the frags for one K-step at a time so the
  // first MFMA's operands complete first and later reads overlap the MFMAs.
#define LDQA(base, h, kk)                                                 \
  _Pragma("unroll") for (int i = 0; i < 4; ++i)                           \
      a[i][kk] = *(const v4i*)&lds[(base) +                               \
          (arow + (h) * 64 + i * 16) * BKB + koff[kk]];
#define LDQB(base, j0, kk)                                                \
  _Pragma("unroll") for (int j = 0; j < 2; ++j)                           \
      b[(j0) + j][kk] = *(const v4i*)&lds[(base) +                        \
          (brow + ((j0) + j) * 16) * BKB + koff[kk]];

#define MM(h, j0)                                                         \
  __builtin_amdgcn_s_setprio(1);                                          \
  _Pragma("unroll") for (int kk = 0; kk < 2; ++kk) {                      \
    _Pragma("unroll") for (int i = 0; i < 4; ++i) {                       \
      _Pragma("unroll") for (int j = 0; j < 2; ++j)                       \
          acc[(h) * 4 + i][(j0) + j] =                                    \
              __builtin_amdgcn_mfma_i32_16x16x64_i8(                      \
                  a[i][kk], b[(j0) + j][kk],                              \
                  acc[(h) * 4 + i][(j0) + j], 0, 0, 0);                   \
    }                                                                     \
  }                                                                       \
  __builtin_amdgcn_s_setprio(0);

  // ---- prologue: tile0 -> buf0 (8 loads), tile1 minus A.q1q3 -> buf1 (6) ----
  STAGE(A0s, gA, 0, 0) STAGE(A0s, gA, 1, 0) STAGE(A0s, gA, 2, 0) STAGE(A0s, gA, 3, 0)
  STAGE(B0s, gB, 0, 0) STAGE(B0s, gB, 1, 0) STAGE(B0s, gB, 2, 0) STAGE(B0s, gB, 3, 0)
  STAGE(A1s, gA, 0, 1) STAGE(A1s, gA, 2, 1)
  STAGE(B1s, gB, 0, 1) STAGE(B1s, gB, 1, 1) STAGE(B1s, gB, 2, 1) STAGE(B1s, gB, 3, 1)
  VMWAIT(6);
  BARRIER();

#pragma unroll 1
  for (int t = 0; t < NKT / 2; ++t) {
    const int kt1 = 2 * t + 1;               // always in range
    const int kt2 = (2 * t + 2) & (NKT - 1); // wraps on last iter (harmless,
    const int kt3 = (2 * t + 3) & (NKT - 1); //  staged regions already consumed)
    // P1: Q(h0,nh0) of buf0; also read P2's b23 (regs free, data gated)
    LDQA(A0s, 0, 0) LDQB(B0s, 0, 0) LDQA(A0s, 0, 1) LDQB(B0s, 0, 1)
    LDQB(B0s, 2, 0) LDQB(B0s, 2, 1)
    STAGE(A1s, gA, 1, kt1) STAGE(A1s, gA, 3, kt1)
    BARRIER();
    MM(0, 0)
    BARRIER();
    // P2: Q(h0,nh1) — reads done in P1
    STAGE(A0s, gA, 0, kt2) STAGE(A0s, gA, 2, kt2)
    BARRIER();
    MM(0, 2)
    BARRIER();
    // P3: Q(h1,nh1)
    LDQA(A0s, 1, 0) LDQA(A0s, 1, 1)
    STAGE(B0s, gB, 0, kt2) STAGE(B0s, gB, 1, kt2)
    BARRIER();
    MM(1, 2)
    BARRIER();
    // P4: Q(h1,nh0) — register-resident; gate buf1 readiness
    STAGE(B0s, gB, 2, kt2) STAGE(B0s, gB, 3, kt2)
    BARRIER();
    MM(1, 0)
    VMWAIT(6);
    BARRIER();
    // P5: Q(h0,nh0) of buf1; also read P6's b23
    LDQA(A1s, 0, 0) LDQB(B1s, 0, 0) LDQA(A1s, 0, 1) LDQB(B1s, 0, 1)
    LDQB(B1s, 2, 0) LDQB(B1s, 2, 1)
    STAGE(A0s, gA, 1, kt2) STAGE(A0s, gA, 3, kt2)
    BARRIER();
    MM(0, 0)
    BARRIER();
    // P6: Q(h0,nh1) — reads done in P5
    STAGE(A1s, gA, 0, kt3) STAGE(A1s, gA, 2, kt3)
    BARRIER();
    MM(0, 2)
    BARRIER();
    // P7: Q(h1,nh1)
    LDQA(A1s, 1, 0) LDQA(A1s, 1, 1)
    STAGE(B1s, gB, 0, kt3) STAGE(B1s, gB, 1, kt3)
    BARRIER();
    MM(1, 2)
    BARRIER();
    // P8: Q(h1,nh0) — gate buf0 readiness for next iter
    STAGE(B1s, gB, 2, kt3) STAGE(B1s, gB, 3, kt3)
    BARRIER();
    MM(1, 0)
    VMWAIT(6);
    BARRIER();
  }
  // Drain stray prefetch DMAs before the block can exit / LDS be reused.
  VMWAIT(0);

  // Epilogue. C/D layout (shape-determined): col = lane&15, row = quad*4+reg
  float bs[4];
#pragma unroll
  for (int j = 0; j < 4; ++j) bs[j] = bias[bn + wc * 64 + j * 16 + r16];

#pragma unroll
  for (int i = 0; i < 8; ++i) {
#pragma unroll
    for (int reg = 0; reg < 4; ++reg) {
      const int m = bm + wr * 128 + i * 16 + quad * 4 + reg;
      const float s = scales[m];
      float* orow = out + (size_t)m * D_OUT + bn + wc * 64 + r16;
#pragma unroll
      for (int j = 0; j < 4; ++j) {
        orow[j * 16] = (float)acc[i][j][reg] * s + bs[j];
      }
    }
  }
}

// ---------------------------------------------------------------------------
extern "C" void kernel_launch(void* const* d_in, const int* in_sizes, int n_in,
                              void* d_out, int out_size, void* d_ws,
                              size_t ws_size, hipStream_t stream) {
  const float* x = (const float*)d_in[0];     // (4,2048,4096) fp32
  const float* w = (const float*)d_in[1];     // (16384,4096) fp32
  const float* bias = (const float*)d_in[2];  // (16384,) fp32
  float* out = (float*)d_out;                 // (4,2048,16384) fp32

  // workspace layout (~96 MB total)
  char* ws = (char*)d_ws;
  double* d_sum = (double*)ws;                          // 8 B @ 0
  double* d_partial = (double*)(ws + 256);              // 16 KB @ 256
  float* d_scales = (float*)(ws + 16640);               // 32 KB
  int8_t* d_xq = (int8_t*)(ws + 49408);                 // 32 MB
  int8_t* d_wq = (int8_t*)(ws + 49408 + (size_t)M_DIM * D_IN);  // 64 MB

  act_quant_kernel<<<M_DIM, 256, 0, stream>>>(x, d_xq, d_scales);
  wabs_kernel<<<2048, 256, 0, stream>>>(w, d_partial);
  wsum_kernel<<<1, 256, 0, stream>>>(d_partial, d_sum);
  wquant_kernel<<<16384, 256, 0, stream>>>(w, d_sum, d_wq);
  gemm_i8_kernel<<<2048, 512, 0, stream>>>(d_xq, d_wq, d_scales, bias, out);
}